// Round 11
// baseline (445.992 us; speedup 1.0000x reference)
//
#include <hip/hip_runtime.h>

// GAT layer, N=8192, D=256. R11: wave-autonomous fp16 flash attention.
//  - wave (wr,sp) owns 16q x 32kv: QK -> mask -> WAVE-LOCAL softmax (shfl,
//    no LDS/barrier) -> intra-wave P transpose (private LDS, lgkm only)
//    -> PV partial (16q x 256d over own kv-half). NPART=4 partials.
//  - 2 barriers/tile (was 3); waves fully decoupled between barriers.
//  - T13 defer-max (THR=8): skip accpv rescale when max growth small.
//  - numerator emitted pre-normalized (accpv/l) -> fp16-safe with defer-max.
//  - grid 512 = exactly 2 blocks/CU x 1 round; XCD-half swizzle.

typedef __attribute__((ext_vector_type(8))) _Float16 f16x8;
typedef __attribute__((ext_vector_type(4))) float f32x4;

#define NN 8192
#define DD 256
#define NSPLIT 2
#define NPART 4
#define CHUNK (NN / NSPLIT)
#define KVB 64
#define BM 32
#define NT (CHUNK / KVB)

#define MFMA16(a, b, c) __builtin_amdgcn_mfma_f32_16x16x32_f16(a, b, c, 0, 0, 0)
#define BAR_LGKM() asm volatile("s_waitcnt lgkmcnt(0)\n\ts_barrier" ::: "memory")
#define BAR_VM() asm volatile("s_waitcnt vmcnt(0)\n\ts_barrier" ::: "memory")

__device__ __forceinline__ short f2h(float f) {
  union { _Float16 h; short s; } u; u.h = (_Float16)f; return u.s;
}
__device__ __forceinline__ float h2f(short b) {
  union { short s; _Float16 h; } u; u.s = b; return (float)u.h;
}

typedef __attribute__((address_space(3))) unsigned lds_u32;
typedef const __attribute__((address_space(1))) unsigned glb_u32;
__device__ __forceinline__ void gl2lds16(const void* g, void* l) {
  __builtin_amdgcn_global_load_lds((glb_u32*)g, (lds_u32*)l, 16, 0, 0);
}

// f32 -> (hi, lo) fp16 split, elementwise
__global__ __launch_bounds__(256) void cvt_split_kernel(const float* __restrict__ in,
                                                        short* __restrict__ hi,
                                                        short* __restrict__ lo, int n) {
  for (int i = blockIdx.x * blockDim.x + threadIdx.x; i < n; i += gridDim.x * blockDim.x) {
    float f = in[i];
    short h = f2h(f);
    hi[i] = h;
    lo[i] = f2h(f - h2f(h));
  }
}

// featT[c][i] = f16(feat[i][c]) via LDS 32x32 tile (coalesced both sides)
__global__ __launch_bounds__(256) void featT_kernel(const float* __restrict__ feat,
                                                    short* __restrict__ fT) {
  __shared__ float tile[32][33];
  const int i0 = blockIdx.x * 32, c0 = blockIdx.y * 32;
  const int r = threadIdx.x >> 5, c = threadIdx.x & 31;
#pragma unroll
  for (int p = 0; p < 4; ++p)
    tile[p * 8 + r][c] = feat[(size_t)(i0 + p * 8 + r) * DD + c0 + c];
  __syncthreads();
#pragma unroll
  for (int p = 0; p < 4; ++p)
    fT[(size_t)(c0 + p * 8 + r) * NN + i0 + c] = f2h(tile[c][p * 8 + r]);
}

// 256x256 f32 -> transposed fp16 (optionally split hi/lo)
__global__ __launch_bounds__(256) void transpose_split_kernel(const float* __restrict__ in,
                                                              short* __restrict__ tHi,
                                                              short* __restrict__ tLo) {
  int r = blockIdx.x, c = threadIdx.x;
  float f = in[r * DD + c];
  short h = f2h(f);
  tHi[c * DD + r] = h;
  if (tLo) tLo[c * DD + r] = f2h(f - h2f(h));
}

// C[64x64 tile] = A @ BT^T over K=256, fp16 MFMA (+split/second/ELU options)
__global__ __launch_bounds__(256) void gemm_kernel(
    const short* __restrict__ Ahi, const short* __restrict__ Alo,
    const short* __restrict__ BThi, const short* __restrict__ BTlo,
    const short* __restrict__ A2, const short* __restrict__ BT2,
    short* __restrict__ outH, float* __restrict__ outF, int doElu) {
  const int lane = threadIdx.x & 63;
  const int w = threadIdx.x >> 6;
  const int l15 = lane & 15;
  const int koff = (lane >> 4) * 8;
  const int row0 = blockIdx.x * 64 + w * 16;
  const int col0 = blockIdx.y * 64;
  f32x4 acc[4] = {};
  const int aoff = (row0 + l15) * DD + koff;
#pragma unroll
  for (int kk = 0; kk < 8; ++kk) {
    f16x8 ah = *(const f16x8*)(Ahi + aoff + kk * 32);
#pragma unroll
    for (int cf = 0; cf < 4; ++cf) {
      int boff = (col0 + cf * 16 + l15) * DD + kk * 32 + koff;
      f16x8 bh = *(const f16x8*)(BThi + boff);
      acc[cf] = MFMA16(ah, bh, acc[cf]);
      if (Alo) {
        f16x8 al = *(const f16x8*)(Alo + aoff + kk * 32);
        acc[cf] = MFMA16(al, bh, acc[cf]);
      }
      if (BTlo) {
        f16x8 bl = *(const f16x8*)(BTlo + boff);
        acc[cf] = MFMA16(ah, bl, acc[cf]);
      }
    }
  }
  if (A2) {
#pragma unroll
    for (int kk = 0; kk < 8; ++kk) {
      f16x8 ah = *(const f16x8*)(A2 + aoff + kk * 32);
#pragma unroll
      for (int cf = 0; cf < 4; ++cf) {
        f16x8 bh = *(const f16x8*)(BT2 + (col0 + cf * 16 + l15) * DD + kk * 32 + koff);
        acc[cf] = MFMA16(ah, bh, acc[cf]);
      }
    }
  }
  const int crow = row0 + (lane >> 4) * 4;
#pragma unroll
  for (int cf = 0; cf < 4; ++cf) {
    int col = col0 + cf * 16 + l15;
#pragma unroll
    for (int r = 0; r < 4; ++r) {
      float v = acc[cf][r];
      if (doElu) v = (v > 0.f) ? v : expm1f(v);
      if (outF) outF[(crow + r) * DD + col] = v;
      if (outH) outH[(crow + r) * DD + col] = f2h(v);
    }
  }
}

// ax[i] = h[i,:]·a1, ay[i] = h[i,:]·a2  (h fp16)
__global__ __launch_bounds__(256) void axay_kernel(const short* __restrict__ hF,
                                                   const float* __restrict__ a1,
                                                   const float* __restrict__ a2,
                                                   float* __restrict__ ax,
                                                   float* __restrict__ ay) {
  const int lane = threadIdx.x & 63;
  const int w = threadIdx.x >> 6;
  const int row = blockIdx.x * 4 + w;
  float s1 = 0.f, s2 = 0.f;
#pragma unroll
  for (int j = 0; j < 4; ++j) {
    int k = lane * 4 + j;
    float hv = h2f(hF[row * DD + k]);
    s1 += hv * a1[k];
    s2 += hv * a2[k];
  }
#pragma unroll
  for (int m = 1; m < 64; m <<= 1) {
    s1 += __shfl_xor(s1, m);
    s2 += __shfl_xor(s2, m);
  }
  if (lane == 0) { ax[row] = s1; ay[row] = s2; }
}

// Wave-autonomous flash attention. Block = 32q, 4 waves = (wr, sp).
// Wave: QK 16q x 32kv -> wave-local softmax -> PV partial 16q x 256d.
__global__ __launch_bounds__(256, 2) void attn_kernel(
    const short* __restrict__ gF, const short* __restrict__ hF,
    const short* __restrict__ fT, const float* __restrict__ ax,
    const float* __restrict__ ay, const int* __restrict__ adj,
    short* __restrict__ numPart, float* __restrict__ mPart,
    float* __restrict__ lPart) {
  __shared__ short sG[BM * DD];    // 16KB g rows (512B rows, XOR-swizzled)
  __shared__ short sH[KVB * DD];   // 32KB h tile (512B rows, XOR-swizzled)
  __shared__ short sP[4][16][40];  // 5KB per-wave P transpose (80B rows)

  const int tid = threadIdx.x;
  const int lane = tid & 63;
  const int w = tid >> 6;
  const int wr = w >> 1, sp = w & 1;
  const int l15 = lane & 15;
  const int q0 = lane >> 4;

  // 512 blocks: XCDs 0-3 -> chunk 0, XCDs 4-7 -> chunk 1
  const int bid = blockIdx.x;
  const int chunk = (bid & 7) >> 2;
  const int rowblk = (bid >> 3) * 4 + (bid & 3);
  const int row0 = rowblk * BM;
  const int jbase = chunk * CHUNK;
  const int pidx = chunk * 2 + sp;

  float ay4[4];
#pragma unroll
  for (int r = 0; r < 4; ++r) ay4[r] = ay[row0 + wr * 16 + q0 * 4 + r];

  // ---- stage sG (32 q rows) once + sH tile 0, XOR-swizzled ----
#pragma unroll
  for (int R = 0; R < 4; ++R) {
    int dstb = R * 4096 + tid * 16;
    int lr = dstb >> 9;
    int srcb = (dstb & 511) ^ ((lr & 7) << 4);
    gl2lds16(gF + (row0 + lr) * DD + (srcb >> 1), (char*)sG + dstb);
  }
  auto stageH = [&](int jrow) {
#pragma unroll
    for (int R = 0; R < 8; ++R) {
      int dstb = R * 4096 + tid * 16;
      int lr = dstb >> 9;
      int srcb = (dstb & 511) ^ ((lr & 7) << 4);
      gl2lds16(hF + (jrow + lr) * DD + (srcb >> 1), (char*)sH + dstb);
    }
  };
  stageH(jbase);

  // ---- adj/ax prefetch tile 0: rows q0*4+r (wr group), cols sp-half ----
  const size_t adjb = (size_t)(row0 + wr * 16 + q0 * 4) * NN;
  int a8[2][4];
  float ax2[2];
#pragma unroll
  for (int cf = 0; cf < 2; ++cf) {
    int kb = jbase + sp * 32 + cf * 16 + l15;
    ax2[cf] = ax[kb];
#pragma unroll
    for (int r = 0; r < 4; ++r) a8[cf][r] = adj[adjb + (size_t)r * NN + kb];
  }

  float m_run[4], l_run[4];
#pragma unroll
  for (int r = 0; r < 4; ++r) { m_run[r] = -__builtin_inff(); l_run[r] = 0.f; }
  f32x4 accpv[16] = {};  // O[q=q0*4+r][d=df*16+l15], this wave's kv-half

  BAR_VM();  // sG + sH(0) + adj staged

  for (int t = 0; t < NT; ++t) {
    const int j0 = jbase + t * KVB;
    // ---- QK: A=g(sG), B=h(sH), single fp16 MFMA, 16q x 32kv ----
    f32x4 aA = {}, aB = {};
    {
      const int lrA = wr * 16 + l15;
      const int rbA = lrA * 512, swzA = (lrA & 7) << 4;
      const int lrB0 = sp * 32 + l15;
      const int rbB0 = lrB0 * 512, swzB0 = (lrB0 & 7) << 4;
      const int lrB1 = lrB0 + 16;
      const int rbB1 = lrB1 * 512, swzB1 = (lrB1 & 7) << 4;
      __builtin_amdgcn_s_setprio(1);
#pragma unroll
      for (int kk = 0; kk < 8; ++kk) {
        const int slot = kk * 64 + q0 * 16;
        f16x8 ga = *(const f16x8*)((const char*)sG + rbA + (slot ^ swzA));
        f16x8 b0 = *(const f16x8*)((const char*)sH + rbB0 + (slot ^ swzB0));
        f16x8 b1 = *(const f16x8*)((const char*)sH + rbB1 + (slot ^ swzB1));
        aA = MFMA16(ga, b0, aA);
        aB = MFMA16(ga, b1, aB);
      }
      __builtin_amdgcn_s_setprio(0);
    }
    BAR_LGKM();  // all waves done reading sH -> safe to restage
    if (t + 1 < NT) stageH(j0 + KVB);
    // ---- adj/ax prefetch (t+1) ----
    int a8n[2][4];
    float ax2n[2];
    {
      int jn = (t + 1 < NT) ? (j0 + KVB) : jbase;
#pragma unroll
      for (int cf = 0; cf < 2; ++cf) {
        int kb = jn + sp * 32 + cf * 16 + l15;
        ax2n[cf] = ax[kb];
#pragma unroll
        for (int r = 0; r < 4; ++r) a8n[cf][r] = adj[adjb + (size_t)r * NN + kb];
      }
    }
    // ---- mask + bias + leaky, all in regs ----
    float s8[2][4];
#pragma unroll
    for (int cf = 0; cf < 2; ++cf)
#pragma unroll
      for (int r = 0; r < 4; ++r) {
        float v = (cf ? aB[r] : aA[r]) + ax2[cf] + ay4[r];
        v = (v > 0.f) ? v : 0.2f * v;
        s8[cf][r] = (a8[cf][r] > 0) ? v : -9.0e15f;
      }
    // ---- wave-local softmax (reduce across l15 group), defer-max ----
    float rowmax[4];
#pragma unroll
    for (int r = 0; r < 4; ++r) rowmax[r] = fmaxf(s8[0][r], s8[1][r]);
#pragma unroll
    for (int msk = 1; msk < 16; msk <<= 1)
#pragma unroll
      for (int r = 0; r < 4; ++r)
        rowmax[r] = fmaxf(rowmax[r], __shfl_xor(rowmax[r], msk));
    int cond = 1;
#pragma unroll
    for (int r = 0; r < 4; ++r) cond &= (rowmax[r] <= m_run[r] + 8.0f);
    const int defer = __all(cond);
    float scale[4];
    if (defer) {
#pragma unroll
      for (int r = 0; r < 4; ++r) scale[r] = 1.0f;
    } else {
#pragma unroll
      for (int r = 0; r < 4; ++r) {
        float mn = fmaxf(m_run[r], rowmax[r]);
        scale[r] = __expf(m_run[r] - mn);
        m_run[r] = mn;
      }
    }
    float psum[4] = {0.f, 0.f, 0.f, 0.f};
    float p8[2][4];
#pragma unroll
    for (int cf = 0; cf < 2; ++cf)
#pragma unroll
      for (int r = 0; r < 4; ++r) {
        float p = __expf(s8[cf][r] - m_run[r]);
        p8[cf][r] = p;
        psum[r] += p;
      }
#pragma unroll
    for (int msk = 1; msk < 16; msk <<= 1)
#pragma unroll
      for (int r = 0; r < 4; ++r) psum[r] += __shfl_xor(psum[r], msk);
#pragma unroll
    for (int r = 0; r < 4; ++r) l_run[r] = l_run[r] * scale[r] + psum[r];
    // ---- intra-wave P transpose (private LDS patch, lgkm-ordered) ----
#pragma unroll
    for (int cf = 0; cf < 2; ++cf)
#pragma unroll
      for (int r = 0; r < 4; ++r)
        sP[w][q0 * 4 + r][cf * 16 + l15] = f2h(p8[cf][r]);
    f16x8 pa = *(const f16x8*)(&sP[w][l15][q0 * 8]);
    // ---- rescale accpv (skipped when defer) ----
    if (!defer) {
#pragma unroll
      for (int df = 0; df < 16; ++df)
#pragma unroll
        for (int r = 0; r < 4; ++r) accpv[df][r] *= scale[r];
    }
    // ---- PV: 16 MFMA over own kv-half, B from global fT (L2-hot) ----
    __builtin_amdgcn_s_setprio(1);
#pragma unroll
    for (int df = 0; df < 16; ++df) {
      f16x8 vb = *(const f16x8*)(fT + (size_t)(df * 16 + l15) * NN +
                                 j0 + sp * 32 + q0 * 8);
      accpv[df] = MFMA16(pa, vb, accpv[df]);
    }
    __builtin_amdgcn_s_setprio(0);
    // rotate prefetch
#pragma unroll
    for (int cf = 0; cf < 2; ++cf) {
#pragma unroll
      for (int r = 0; r < 4; ++r) a8[cf][r] = a8n[cf][r];
      ax2[cf] = ax2n[cf];
    }
    BAR_VM();  // stage(t+1) complete; all waves synced
  }
  // ---- emit partials (numerator pre-normalized by l -> fp16-safe) ----
  float inv[4];
#pragma unroll
  for (int r = 0; r < 4; ++r) inv[r] = 1.0f / l_run[r];
  if (l15 == 0) {
#pragma unroll
    for (int r = 0; r < 4; ++r) {
      int row = row0 + wr * 16 + q0 * 4 + r;
      mPart[pidx * NN + row] = m_run[r];
      lPart[pidx * NN + row] = l_run[r];
    }
  }
  short* np = numPart + (size_t)pidx * NN * DD;
#pragma unroll
  for (int df = 0; df < 16; ++df)
#pragma unroll
    for (int r = 0; r < 4; ++r)
      np[(size_t)(row0 + wr * 16 + q0 * 4 + r) * DD + df * 16 + l15] =
          f2h(accpv[df][r] * inv[r]);
}

// hp = sum_i nbar_i * (l_i * e^{m_i-m*}) / sum_i (l_i * e^{m_i-m*})
__global__ __launch_bounds__(256) void combine_kernel(
    const short* __restrict__ nbar, const float* __restrict__ mPart,
    const float* __restrict__ lPart, short* __restrict__ hp) {
  const int row = blockIdx.x;
  const int col = threadIdx.x;
  float m[NPART], l[NPART];
  float ms = -__builtin_inff();
#pragma unroll
  for (int i = 0; i < NPART; ++i) {
    m[i] = mPart[i * NN + row];
    l[i] = lPart[i * NN + row];
    ms = fmaxf(ms, m[i]);
  }
  float denom = 0.f, num = 0.f;
  const size_t idx = (size_t)row * DD + col;
#pragma unroll
  for (int i = 0; i < NPART; ++i) {
    float wgt = __expf(m[i] - ms) * l[i];
    denom += wgt;
    num += h2f(nbar[(size_t)i * NN * DD + idx]) * wgt;
  }
  hp[idx] = f2h(num / denom);
}

extern "C" void kernel_launch(void* const* d_in, const int* in_sizes, int n_in,
                              void* d_out, int out_size, void* d_ws, size_t ws_size,
                              hipStream_t stream) {
  const float* feat = (const float*)d_in[0];
  const int*   adj  = (const int*)d_in[1];
  const float* W    = (const float*)d_in[2];
  const float* a1   = (const float*)d_in[3];
  const float* a2   = (const float*)d_in[4];
  const float* a12  = (const float*)d_in[5];
  const float* W1   = (const float*)d_in[6];
  const float* W2   = (const float*)d_in[7];
  float* out = (float*)d_out;
  (void)in_sizes; (void)n_in; (void)out_size; (void)ws_size;

  char* ws = (char*)d_ws;
  size_t off = 0;
  auto alloc = [&](size_t b) { void* p = ws + off; off += (b + 255) & ~(size_t)255; return p; };
  short* featHi = (short*)alloc((size_t)NN * DD * 2);
  short* featLo = (short*)alloc((size_t)NN * DD * 2);
  short* fT     = (short*)alloc((size_t)NN * DD * 2);
  short* hF     = (short*)alloc((size_t)NN * DD * 2);
  short* gF     = (short*)alloc((size_t)NN * DD * 2);
  short* hp     = (short*)alloc((size_t)NN * DD * 2);
  short* WTh    = (short*)alloc((size_t)DD * DD * 2);
  short* WTl    = (short*)alloc((size_t)DD * DD * 2);
  short* A12Th  = (short*)alloc((size_t)DD * DD * 2);
  short* A12Tl  = (short*)alloc((size_t)DD * DD * 2);
  short* W1T    = (short*)alloc((size_t)DD * DD * 2);
  short* W2T    = (short*)alloc((size_t)DD * DD * 2);
  float* axv    = (float*)alloc((size_t)NN * 4);
  float* ayv    = (float*)alloc((size_t)NN * 4);
  short* numPart = (short*)alloc((size_t)NPART * NN * DD * 2);
  float* mPart   = (float*)alloc((size_t)NPART * NN * 4);
  float* lPart   = (float*)alloc((size_t)NPART * NN * 4);

  cvt_split_kernel<<<2048, 256, 0, stream>>>(feat, featHi, featLo, NN * DD);
  featT_kernel<<<dim3(NN / 32, DD / 32), 256, 0, stream>>>(feat, fT);
  transpose_split_kernel<<<DD, DD, 0, stream>>>(W, WTh, WTl);
  transpose_split_kernel<<<DD, DD, 0, stream>>>(a12, A12Th, A12Tl);
  transpose_split_kernel<<<DD, DD, 0, stream>>>(W1, W1T, nullptr);
  transpose_split_kernel<<<DD, DD, 0, stream>>>(W2, W2T, nullptr);
  // h = feat @ W (split-fp16 3-term), stored fp16
  gemm_kernel<<<dim3(NN / 64, DD / 64), 256, 0, stream>>>(
      featHi, featLo, WTh, WTl, nullptr, nullptr, hF, nullptr, 0);
  // g = h @ a12 (2-term), stored fp16
  gemm_kernel<<<dim3(NN / 64, DD / 64), 256, 0, stream>>>(
      hF, nullptr, A12Th, A12Tl, nullptr, nullptr, gF, nullptr, 0);
  axay_kernel<<<NN / 4, 256, 0, stream>>>(hF, a1, a2, axv, ayv);
  attn_kernel<<<dim3((NN / BM) * NSPLIT), 256, 0, stream>>>(
      gF, hF, fT, axv, ayv, adj, numPart, mPart, lPart);
  combine_kernel<<<NN, DD, 0, stream>>>(numPart, mPart, lPart, hp);
  // out = elu(feat@W1 + h'@W2)
  gemm_kernel<<<dim3(NN / 64, DD / 64), 256, 0, stream>>>(
      featHi, nullptr, W1T, nullptr, hp, W2T, nullptr, out, 1);
}

// Round 12
// 352.864 us; speedup vs baseline: 1.2639x; 1.2639x over previous
//
#include <hip/hip_runtime.h>

// GAT layer, N=8192, D=256. R12 = R10 dataflow + dbuf-sH(KVB=32) + NSPLIT=2.
//  - stage(t+1) issued at TOP of tile t into the other sH buffer -> its
//    completion has a full tile of flight time, off the critical chain.
//  - issue order vb -> adj -> stage keeps PV's vmcnt wait on vb only.
//  - 512 blocks = 2/CU x exactly 1 residency round; XCD-half swizzle.
// fp16 numerics as R10 (split-fp16 3-term for h; single fp16 QK^T MFMA).

typedef __attribute__((ext_vector_type(8))) _Float16 f16x8;
typedef __attribute__((ext_vector_type(4))) short s16x4;
typedef __attribute__((ext_vector_type(4))) float f32x4;

#define NN 8192
#define DD 256
#define NSPLIT 2
#define NPART 2
#define CHUNK (NN / NSPLIT)
#define KVB 32
#define BM 32
#define NT (CHUNK / KVB)

#define MFMA16(a, b, c) __builtin_amdgcn_mfma_f32_16x16x32_f16(a, b, c, 0, 0, 0)
#define BAR_LGKM() asm volatile("s_waitcnt lgkmcnt(0)\n\ts_barrier" ::: "memory")
#define BAR_VM() asm volatile("s_waitcnt vmcnt(0)\n\ts_barrier" ::: "memory")

__device__ __forceinline__ short f2h(float f) {
  union { _Float16 h; short s; } u; u.h = (_Float16)f; return u.s;
}
__device__ __forceinline__ float h2f(short b) {
  union { short s; _Float16 h; } u; u.s = b; return (float)u.h;
}

typedef __attribute__((address_space(3))) unsigned lds_u32;
typedef const __attribute__((address_space(1))) unsigned glb_u32;
__device__ __forceinline__ void gl2lds16(const void* g, void* l) {
  __builtin_amdgcn_global_load_lds((glb_u32*)g, (lds_u32*)l, 16, 0, 0);
}

// f32 -> (hi, lo) fp16 split, elementwise
__global__ __launch_bounds__(256) void cvt_split_kernel(const float* __restrict__ in,
                                                        short* __restrict__ hi,
                                                        short* __restrict__ lo, int n) {
  for (int i = blockIdx.x * blockDim.x + threadIdx.x; i < n; i += gridDim.x * blockDim.x) {
    float f = in[i];
    short h = f2h(f);
    hi[i] = h;
    lo[i] = f2h(f - h2f(h));
  }
}

// featT[c][i] = f16(feat[i][c]) via LDS 32x32 tile (coalesced both sides)
__global__ __launch_bounds__(256) void featT_kernel(const float* __restrict__ feat,
                                                    short* __restrict__ fT) {
  __shared__ float tile[32][33];
  const int i0 = blockIdx.x * 32, c0 = blockIdx.y * 32;
  const int r = threadIdx.x >> 5, c = threadIdx.x & 31;
#pragma unroll
  for (int p = 0; p < 4; ++p)
    tile[p * 8 + r][c] = feat[(size_t)(i0 + p * 8 + r) * DD + c0 + c];
  __syncthreads();
#pragma unroll
  for (int p = 0; p < 4; ++p)
    fT[(size_t)(c0 + p * 8 + r) * NN + i0 + c] = f2h(tile[c][p * 8 + r]);
}

// 256x256 f32 -> transposed fp16 (optionally split hi/lo)
__global__ __launch_bounds__(256) void transpose_split_kernel(const float* __restrict__ in,
                                                              short* __restrict__ tHi,
                                                              short* __restrict__ tLo) {
  int r = blockIdx.x, c = threadIdx.x;
  float f = in[r * DD + c];
  short h = f2h(f);
  tHi[c * DD + r] = h;
  if (tLo) tLo[c * DD + r] = f2h(f - h2f(h));
}

// C[64x64 tile] = A @ BT^T over K=256, fp16 MFMA (+split/second/ELU options)
__global__ __launch_bounds__(256) void gemm_kernel(
    const short* __restrict__ Ahi, const short* __restrict__ Alo,
    const short* __restrict__ BThi, const short* __restrict__ BTlo,
    const short* __restrict__ A2, const short* __restrict__ BT2,
    short* __restrict__ outH, float* __restrict__ outF, int doElu) {
  const int lane = threadIdx.x & 63;
  const int w = threadIdx.x >> 6;
  const int l15 = lane & 15;
  const int koff = (lane >> 4) * 8;
  const int row0 = blockIdx.x * 64 + w * 16;
  const int col0 = blockIdx.y * 64;
  f32x4 acc[4] = {};
  const int aoff = (row0 + l15) * DD + koff;
#pragma unroll
  for (int kk = 0; kk < 8; ++kk) {
    f16x8 ah = *(const f16x8*)(Ahi + aoff + kk * 32);
#pragma unroll
    for (int cf = 0; cf < 4; ++cf) {
      int boff = (col0 + cf * 16 + l15) * DD + kk * 32 + koff;
      f16x8 bh = *(const f16x8*)(BThi + boff);
      acc[cf] = MFMA16(ah, bh, acc[cf]);
      if (Alo) {
        f16x8 al = *(const f16x8*)(Alo + aoff + kk * 32);
        acc[cf] = MFMA16(al, bh, acc[cf]);
      }
      if (BTlo) {
        f16x8 bl = *(const f16x8*)(BTlo + boff);
        acc[cf] = MFMA16(ah, bl, acc[cf]);
      }
    }
  }
  if (A2) {
#pragma unroll
    for (int kk = 0; kk < 8; ++kk) {
      f16x8 ah = *(const f16x8*)(A2 + aoff + kk * 32);
#pragma unroll
      for (int cf = 0; cf < 4; ++cf) {
        f16x8 bh = *(const f16x8*)(BT2 + (col0 + cf * 16 + l15) * DD + kk * 32 + koff);
        acc[cf] = MFMA16(ah, bh, acc[cf]);
      }
    }
  }
  const int crow = row0 + (lane >> 4) * 4;
#pragma unroll
  for (int cf = 0; cf < 4; ++cf) {
    int col = col0 + cf * 16 + l15;
#pragma unroll
    for (int r = 0; r < 4; ++r) {
      float v = acc[cf][r];
      if (doElu) v = (v > 0.f) ? v : expm1f(v);
      if (outF) outF[(crow + r) * DD + col] = v;
      if (outH) outH[(crow + r) * DD + col] = f2h(v);
    }
  }
}

// ax[i] = h[i,:]·a1, ay[i] = h[i,:]·a2  (h fp16)
__global__ __launch_bounds__(256) void axay_kernel(const short* __restrict__ hF,
                                                   const float* __restrict__ a1,
                                                   const float* __restrict__ a2,
                                                   float* __restrict__ ax,
                                                   float* __restrict__ ay) {
  const int lane = threadIdx.x & 63;
  const int w = threadIdx.x >> 6;
  const int row = blockIdx.x * 4 + w;
  float s1 = 0.f, s2 = 0.f;
#pragma unroll
  for (int j = 0; j < 4; ++j) {
    int k = lane * 4 + j;
    float hv = h2f(hF[row * DD + k]);
    s1 += hv * a1[k];
    s2 += hv * a2[k];
  }
#pragma unroll
  for (int m = 1; m < 64; m <<= 1) {
    s1 += __shfl_xor(s1, m);
    s2 += __shfl_xor(s2, m);
  }
  if (lane == 0) { ax[row] = s1; ay[row] = s2; }
}

// Flash attention, fp16, 32q x 32kv tiles, double-buffered h staging.
__global__ __launch_bounds__(256, 2) void attn_kernel(
    const short* __restrict__ gF, const short* __restrict__ hF,
    const short* __restrict__ fT, const float* __restrict__ ax,
    const float* __restrict__ ay, const int* __restrict__ adj,
    short* __restrict__ numPart, float* __restrict__ mPart,
    float* __restrict__ lPart) {
  __shared__ short sG[BM * DD];       // 16KB g tile (512B rows, XOR-swizzled)
  __shared__ short sH[2][KVB * DD];   // 2x16KB h dbuf (512B rows, swizzled)
  __shared__ float sS[BM][36];        // 4.5KB S exchange
  __shared__ short sP[BM][40];        // 2.5KB P exchange
  __shared__ float sScale[BM];

  const int tid = threadIdx.x;
  const int lane = tid & 63;
  const int w = tid >> 6;
  const int wr = w >> 1, sp = w & 1;
  const int l15 = lane & 15;
  const int q0 = lane >> 4;
  const int crow = q0 * 4;

  // 512 blocks: XCDs 0-3 -> chunk 0, XCDs 4-7 -> chunk 1
  const int bid = blockIdx.x;
  const int chunk = (bid & 7) >> 2;
  const int rowblk = (bid >> 3) * 4 + (bid & 3);
  const int row0 = rowblk * BM;
  const int jbase = chunk * CHUNK;

  float ay4[4];
#pragma unroll
  for (int r = 0; r < 4; ++r) ay4[r] = ay[row0 + wr * 16 + crow + r];

  // ---- stage sG once + sH[0] tile 0, XOR-swizzled ----
#pragma unroll
  for (int R = 0; R < 4; ++R) {
    int dstb = R * 4096 + tid * 16;
    int lr = dstb >> 9;
    int srcb = (dstb & 511) ^ ((lr & 7) << 4);
    gl2lds16(gF + (row0 + lr) * DD + (srcb >> 1), (char*)sG + dstb);
  }
  auto stageH = [&](int buf, int jrow) {
#pragma unroll
    for (int R = 0; R < 4; ++R) {
      int dstb = R * 4096 + tid * 16;
      int lr = dstb >> 9;
      int srcb = (dstb & 511) ^ ((lr & 7) << 4);
      gl2lds16(hF + (jrow + lr) * DD + (srcb >> 1), (char*)sH[buf] + dstb);
    }
  };
  stageH(0, jbase);

  const size_t adjrow = (size_t)(row0 + wr * 16 + crow) * NN;
  // ---- adj/ax prefetch tile 0 ----
  int a4[4];
  float axv;
  {
    int kb = jbase + sp * 16 + l15;
#pragma unroll
    for (int r = 0; r < 4; ++r) a4[r] = adj[adjrow + (size_t)r * NN + kb];
    axv = ax[kb];
  }

  const int srow = tid >> 3;
  const int sc4 = (tid & 7) * 4;
  float m_run = -__builtin_inff();
  float l_run = 0.f;
  f32x4 accpv[2][4] = {};  // [rg][df]: rows rg*16+crow+r, dims w*64+df*16+l15

  BAR_VM();  // prologue staging complete

  for (int t = 0; t < NT; ++t) {
    const int j0 = jbase + t * KVB;
    // ---- issue order: vb(t) -> adj(t+1) -> stage(t+1); PV waits only vb ----
    f16x8 vb[4];
#pragma unroll
    for (int df = 0; df < 4; ++df)
      vb[df] = *(const f16x8*)(fT + (size_t)(w * 64 + df * 16 + l15) * NN + j0 + q0 * 8);
    int a4n[4];
    float axn;
    {
      int jn = (t + 1 < NT) ? (j0 + KVB) : jbase;
      int kb = jn + sp * 16 + l15;
#pragma unroll
      for (int r = 0; r < 4; ++r) a4n[r] = adj[adjrow + (size_t)r * NN + kb];
      axn = ax[kb];
    }
    if (t + 1 < NT) stageH((t + 1) & 1, j0 + KVB);  // dest buffer idle since QK(t-1)
    // ---- QK(t): A=g(sG), B=h(sH[t&1]), 8 fp16 MFMA, 16q x 16kv ----
    f32x4 acc = {};
    {
      const int lrA = wr * 16 + l15;
      const int rbA = lrA * 512, swzA = (lrA & 7) << 4;
      const int lrB = sp * 16 + l15;
      const int rbB = lrB * 512, swzB = (lrB & 7) << 4;
      const char* sHb = (const char*)sH[t & 1];
      __builtin_amdgcn_s_setprio(1);
#pragma unroll
      for (int kk = 0; kk < 8; ++kk) {
        const int slot = kk * 64 + q0 * 16;
        f16x8 ga = *(const f16x8*)((const char*)sG + rbA + (slot ^ swzA));
        f16x8 bh = *(const f16x8*)(sHb + rbB + (slot ^ swzB));
        acc = MFMA16(ga, bh, acc);
      }
      __builtin_amdgcn_s_setprio(0);
    }
    // ---- mask + bias + leaky -> sS ----
#pragma unroll
    for (int r = 0; r < 4; ++r) {
      float v = acc[r] + axv + ay4[r];
      v = (v > 0.f) ? v : 0.2f * v;
      sS[wr * 16 + crow + r][sp * 16 + l15] = (a4[r] > 0) ? v : -9.0e15f;
    }
    BAR_LGKM();  // sS visible
    // ---- softmax: 8 threads/row, 4 cols each ----
    {
      float4 sv = *(const float4*)(&sS[srow][sc4]);
      float tmax = fmaxf(fmaxf(sv.x, sv.y), fmaxf(sv.z, sv.w));
      tmax = fmaxf(tmax, __shfl_xor(tmax, 1));
      tmax = fmaxf(tmax, __shfl_xor(tmax, 2));
      tmax = fmaxf(tmax, __shfl_xor(tmax, 4));
      float m_new = fmaxf(m_run, tmax);
      float scale = __expf(m_run - m_new);
      float p0 = __expf(sv.x - m_new), p1 = __expf(sv.y - m_new);
      float p2 = __expf(sv.z - m_new), p3 = __expf(sv.w - m_new);
      float psum = (p0 + p1) + (p2 + p3);
      psum += __shfl_xor(psum, 1);
      psum += __shfl_xor(psum, 2);
      psum += __shfl_xor(psum, 4);
      l_run = l_run * scale + psum;
      m_run = m_new;
      union { short s[4]; s16x4 v; } pu;
      pu.s[0] = f2h(p0); pu.s[1] = f2h(p1); pu.s[2] = f2h(p2); pu.s[3] = f2h(p3);
      *(s16x4*)(&sP[srow][sc4]) = pu.v;
      if ((tid & 7) == 0) sScale[srow] = scale;
    }
    BAR_LGKM();  // sP/sScale visible
    // ---- PV: rescale + 8 MFMA (A=sP, B=vb regs) ----
    {
      float4 sc0 = *(const float4*)(&sScale[crow]);
      float4 sc1 = *(const float4*)(&sScale[16 + crow]);
      const float* scp[2] = { &sc0.x, &sc1.x };
#pragma unroll
      for (int rg = 0; rg < 2; ++rg)
#pragma unroll
        for (int df = 0; df < 4; ++df)
#pragma unroll
          for (int r = 0; r < 4; ++r) accpv[rg][df][r] *= scp[rg][r];
      f16x8 pa0 = *(const f16x8*)(&sP[l15][q0 * 8]);
      f16x8 pa1 = *(const f16x8*)(&sP[16 + l15][q0 * 8]);
      __builtin_amdgcn_s_setprio(1);
#pragma unroll
      for (int df = 0; df < 4; ++df) {
        accpv[0][df] = MFMA16(pa0, vb[df], accpv[0][df]);
        accpv[1][df] = MFMA16(pa1, vb[df], accpv[1][df]);
      }
      __builtin_amdgcn_s_setprio(0);
    }
    // rotate adj/ax prefetch
#pragma unroll
    for (int r = 0; r < 4; ++r) a4[r] = a4n[r];
    axv = axn;
    BAR_VM();  // stage(t+1) had a full tile in flight; sS/sP reusable
  }
  // ---- emit partials ----
  if ((tid & 7) == 0) {
    mPart[chunk * NN + row0 + srow] = m_run;
    lPart[chunk * NN + row0 + srow] = l_run;
  }
  short* np = numPart + (size_t)chunk * NN * DD;
#pragma unroll
  for (int rg = 0; rg < 2; ++rg)
#pragma unroll
    for (int df = 0; df < 4; ++df) {
      int col = w * 64 + df * 16 + l15;
#pragma unroll
      for (int r = 0; r < 4; ++r)
        np[(size_t)(row0 + rg * 16 + crow + r) * DD + col] = f2h(accpv[rg][df][r]);
    }
}

// hp = (sum_i num_i * exp(m_i - m*)) / (sum_i l_i * exp(m_i - m*))
__global__ __launch_bounds__(256) void combine_kernel(
    const short* __restrict__ numPart, const float* __restrict__ mPart,
    const float* __restrict__ lPart, short* __restrict__ hp) {
  const int row = blockIdx.x;
  const int col = threadIdx.x;
  float m[NPART], l[NPART];
  float ms = -__builtin_inff();
#pragma unroll
  for (int i = 0; i < NPART; ++i) {
    m[i] = mPart[i * NN + row];
    l[i] = lPart[i * NN + row];
    ms = fmaxf(ms, m[i]);
  }
  float denom = 0.f, num = 0.f;
  const size_t idx = (size_t)row * DD + col;
#pragma unroll
  for (int i = 0; i < NPART; ++i) {
    float wgt = __expf(m[i] - ms);
    denom += l[i] * wgt;
    num += h2f(numPart[(size_t)i * NN * DD + idx]) * wgt;
  }
  hp[idx] = f2h(num / denom);
}

extern "C" void kernel_launch(void* const* d_in, const int* in_sizes, int n_in,
                              void* d_out, int out_size, void* d_ws, size_t ws_size,
                              hipStream_t stream) {
  const float* feat = (const float*)d_in[0];
  const int*   adj  = (const int*)d_in[1];
  const float* W    = (const float*)d_in[2];
  const float* a1   = (const float*)d_in[3];
  const float* a2   = (const float*)d_in[4];
  const float* a12  = (const float*)d_in[5];
  const float* W1   = (const float*)d_in[6];
  const float* W2   = (const float*)d_in[7];
  float* out = (float*)d_out;
  (void)in_sizes; (void)n_in; (void)out_size; (void)ws_size;

  char* ws = (char*)d_ws;
  size_t off = 0;
  auto alloc = [&](size_t b) { void* p = ws + off; off += (b + 255) & ~(size_t)255; return p; };
  short* featHi = (short*)alloc((size_t)NN * DD * 2);
  short* featLo = (short*)alloc((size_t)NN * DD * 2);
  short* fT     = (short*)alloc((size_t)NN * DD * 2);
  short* hF     = (short*)alloc((size_t)NN * DD * 2);
  short* gF     = (short*)alloc((size_t)NN * DD * 2);
  short* hp     = (short*)alloc((size_t)NN * DD * 2);
  short* WTh    = (short*)alloc((size_t)DD * DD * 2);
  short* WTl    = (short*)alloc((size_t)DD * DD * 2);
  short* A12Th  = (short*)alloc((size_t)DD * DD * 2);
  short* A12Tl  = (short*)alloc((size_t)DD * DD * 2);
  short* W1T    = (short*)alloc((size_t)DD * DD * 2);
  short* W2T    = (short*)alloc((size_t)DD * DD * 2);
  float* axv    = (float*)alloc((size_t)NN * 4);
  float* ayv    = (float*)alloc((size_t)NN * 4);
  short* numPart = (short*)alloc((size_t)NPART * NN * DD * 2);
  float* mPart   = (float*)alloc((size_t)NPART * NN * 4);
  float* lPart   = (float*)alloc((size_t)NPART * NN * 4);

  cvt_split_kernel<<<2048, 256, 0, stream>>>(feat, featHi, featLo, NN * DD);
  featT_kernel<<<dim3(NN / 32, DD / 32), 256, 0, stream>>>(feat, fT);
  transpose_split_kernel<<<DD, DD, 0, stream>>>(W, WTh, WTl);
  transpose_split_kernel<<<DD, DD, 0, stream>>>(a12, A12Th, A12Tl);
  transpose_split_kernel<<<DD, DD, 0, stream>>>(W1, W1T, nullptr);
  transpose_split_kernel<<<DD, DD, 0, stream>>>(W2, W2T, nullptr);
  // h = feat @ W (split-fp16 3-term), stored fp16
  gemm_kernel<<<dim3(NN / 64, DD / 64), 256, 0, stream>>>(
      featHi, featLo, WTh, WTl, nullptr, nullptr, hF, nullptr, 0);
  // g = h @ a12 (2-term), stored fp16
  gemm_kernel<<<dim3(NN / 64, DD / 64), 256, 0, stream>>>(
      hF, nullptr, A12Th, A12Tl, nullptr, nullptr, gF, nullptr, 0);
  axay_kernel<<<NN / 4, 256, 0, stream>>>(hF, a1, a2, axv, ayv);
  attn_kernel<<<dim3((NN / BM) * NSPLIT), 256, 0, stream>>>(
      gF, hF, fT, axv, ayv, adj, numPart, mPart, lPart);
  combine_kernel<<<NN, DD, 0, stream>>>(numPart, mPart, lPart, hp);
  // out = elu(feat@W1 + h'@W2)
  gemm_kernel<<<dim3(NN / 64, DD / 64), 256, 0, stream>>>(
      featHi, nullptr, W1T, nullptr, hp, W2T, nullptr, out, 1);
}

// Round 13
// 335.705 us; speedup vs baseline: 1.3285x; 1.0511x over previous
//
#include <hip/hip_runtime.h>

// GAT layer, N=8192, D=256. R13 = R10 (best, 231us attn) + adj bit-packing
// + NSPLIT=2 single residency round.
//  - adjpack: 256MB int32 -> 8MB bitmask. Frees per-XCD L2 (adj slices were
//    ~8MB/XCD, evicting h/fT); stage+vb loads become L2 hits.
//  - attn identical to R10 otherwise: KVB=64, fp16 single-MFMA QK, 3
//    barriers/tile, vb-before-stage vmcnt discipline, XOR-swizzled LDS.

typedef __attribute__((ext_vector_type(8))) _Float16 f16x8;
typedef __attribute__((ext_vector_type(4))) float f32x4;

#define NN 8192
#define DD 256
#define NSPLIT 2
#define NPART 2
#define CHUNK (NN / NSPLIT)
#define KVB 64
#define BM 32
#define NT (CHUNK / KVB)
#define NW (NN / 32)  // adj words per row

#define MFMA16(a, b, c) __builtin_amdgcn_mfma_f32_16x16x32_f16(a, b, c, 0, 0, 0)
#define BAR_LGKM() asm volatile("s_waitcnt lgkmcnt(0)\n\ts_barrier" ::: "memory")
#define BAR_VM() asm volatile("s_waitcnt vmcnt(0)\n\ts_barrier" ::: "memory")

__device__ __forceinline__ short f2h(float f) {
  union { _Float16 h; short s; } u; u.h = (_Float16)f; return u.s;
}
__device__ __forceinline__ float h2f(short b) {
  union { short s; _Float16 h; } u; u.s = b; return (float)u.h;
}

typedef __attribute__((address_space(3))) unsigned lds_u32;
typedef const __attribute__((address_space(1))) unsigned glb_u32;
__device__ __forceinline__ void gl2lds16(const void* g, void* l) {
  __builtin_amdgcn_global_load_lds((glb_u32*)g, (lds_u32*)l, 16, 0, 0);
}

// adj int32 -> bitmask (1 word = 32 entries per thread)
__global__ __launch_bounds__(256) void adjpack_kernel(const int* __restrict__ adj,
                                                      unsigned* __restrict__ adjp) {
  size_t wrd = (size_t)blockIdx.x * 256 + threadIdx.x;
  const int* src = adj + wrd * 32;
  unsigned m = 0;
#pragma unroll
  for (int i = 0; i < 32; i += 4) {
    int4 v = *(const int4*)(src + i);
    m |= (unsigned)(v.x > 0) << i;
    m |= (unsigned)(v.y > 0) << (i + 1);
    m |= (unsigned)(v.z > 0) << (i + 2);
    m |= (unsigned)(v.w > 0) << (i + 3);
  }
  adjp[wrd] = m;
}

// f32 -> (hi, lo) fp16 split, elementwise
__global__ __launch_bounds__(256) void cvt_split_kernel(const float* __restrict__ in,
                                                        short* __restrict__ hi,
                                                        short* __restrict__ lo, int n) {
  for (int i = blockIdx.x * blockDim.x + threadIdx.x; i < n; i += gridDim.x * blockDim.x) {
    float f = in[i];
    short h = f2h(f);
    hi[i] = h;
    lo[i] = f2h(f - h2f(h));
  }
}

// featT[c][i] = f16(feat[i][c]) via LDS 32x32 tile (coalesced both sides)
__global__ __launch_bounds__(256) void featT_kernel(const float* __restrict__ feat,
                                                    short* __restrict__ fT) {
  __shared__ float tile[32][33];
  const int i0 = blockIdx.x * 32, c0 = blockIdx.y * 32;
  const int r = threadIdx.x >> 5, c = threadIdx.x & 31;
#pragma unroll
  for (int p = 0; p < 4; ++p)
    tile[p * 8 + r][c] = feat[(size_t)(i0 + p * 8 + r) * DD + c0 + c];
  __syncthreads();
#pragma unroll
  for (int p = 0; p < 4; ++p)
    fT[(size_t)(c0 + p * 8 + r) * NN + i0 + c] = f2h(tile[c][p * 8 + r]);
}

// 256x256 f32 -> transposed fp16 (optionally split hi/lo)
__global__ __launch_bounds__(256) void transpose_split_kernel(const float* __restrict__ in,
                                                              short* __restrict__ tHi,
                                                              short* __restrict__ tLo) {
  int r = blockIdx.x, c = threadIdx.x;
  float f = in[r * DD + c];
  short h = f2h(f);
  tHi[c * DD + r] = h;
  if (tLo) tLo[c * DD + r] = f2h(f - h2f(h));
}

// C[64x64 tile] = A @ BT^T over K=256, fp16 MFMA (+split/second/ELU options)
__global__ __launch_bounds__(256) void gemm_kernel(
    const short* __restrict__ Ahi, const short* __restrict__ Alo,
    const short* __restrict__ BThi, const short* __restrict__ BTlo,
    const short* __restrict__ A2, const short* __restrict__ BT2,
    short* __restrict__ outH, float* __restrict__ outF, int doElu) {
  const int lane = threadIdx.x & 63;
  const int w = threadIdx.x >> 6;
  const int l15 = lane & 15;
  const int koff = (lane >> 4) * 8;
  const int row0 = blockIdx.x * 64 + w * 16;
  const int col0 = blockIdx.y * 64;
  f32x4 acc[4] = {};
  const int aoff = (row0 + l15) * DD + koff;
#pragma unroll
  for (int kk = 0; kk < 8; ++kk) {
    f16x8 ah = *(const f16x8*)(Ahi + aoff + kk * 32);
#pragma unroll
    for (int cf = 0; cf < 4; ++cf) {
      int boff = (col0 + cf * 16 + l15) * DD + kk * 32 + koff;
      f16x8 bh = *(const f16x8*)(BThi + boff);
      acc[cf] = MFMA16(ah, bh, acc[cf]);
      if (Alo) {
        f16x8 al = *(const f16x8*)(Alo + aoff + kk * 32);
        acc[cf] = MFMA16(al, bh, acc[cf]);
      }
      if (BTlo) {
        f16x8 bl = *(const f16x8*)(BTlo + boff);
        acc[cf] = MFMA16(ah, bl, acc[cf]);
      }
    }
  }
  if (A2) {
#pragma unroll
    for (int kk = 0; kk < 8; ++kk) {
      f16x8 ah = *(const f16x8*)(A2 + aoff + kk * 32);
#pragma unroll
      for (int cf = 0; cf < 4; ++cf) {
        f16x8 bh = *(const f16x8*)(BT2 + (col0 + cf * 16 + l15) * DD + kk * 32 + koff);
        acc[cf] = MFMA16(ah, bh, acc[cf]);
      }
    }
  }
  const int crow = row0 + (lane >> 4) * 4;
#pragma unroll
  for (int cf = 0; cf < 4; ++cf) {
    int col = col0 + cf * 16 + l15;
#pragma unroll
    for (int r = 0; r < 4; ++r) {
      float v = acc[cf][r];
      if (doElu) v = (v > 0.f) ? v : expm1f(v);
      if (outF) outF[(crow + r) * DD + col] = v;
      if (outH) outH[(crow + r) * DD + col] = f2h(v);
    }
  }
}

// ax[i] = h[i,:]·a1, ay[i] = h[i,:]·a2  (h fp16)
__global__ __launch_bounds__(256) void axay_kernel(const short* __restrict__ hF,
                                                   const float* __restrict__ a1,
                                                   const float* __restrict__ a2,
                                                   float* __restrict__ ax,
                                                   float* __restrict__ ay) {
  const int lane = threadIdx.x & 63;
  const int w = threadIdx.x >> 6;
  const int row = blockIdx.x * 4 + w;
  float s1 = 0.f, s2 = 0.f;
#pragma unroll
  for (int j = 0; j < 4; ++j) {
    int k = lane * 4 + j;
    float hv = h2f(hF[row * DD + k]);
    s1 += hv * a1[k];
    s2 += hv * a2[k];
  }
#pragma unroll
  for (int m = 1; m < 64; m <<= 1) {
    s1 += __shfl_xor(s1, m);
    s2 += __shfl_xor(s2, m);
  }
  if (lane == 0) { ax[row] = s1; ay[row] = s2; }
}

// Flash attention (R10 structure), packed-adj masks. 32q x 64kv, 4 waves.
__global__ __launch_bounds__(256, 2) void attn_kernel(
    const short* __restrict__ gF, const short* __restrict__ hF,
    const short* __restrict__ fT, const float* __restrict__ ax,
    const float* __restrict__ ay, const unsigned* __restrict__ adjp,
    short* __restrict__ numPart, float* __restrict__ mPart,
    float* __restrict__ lPart) {
  __shared__ short sG[BM * DD];     // 16KB g tile (512B rows, XOR-swizzled)
  __shared__ short sH[KVB * DD];    // 32KB h tile (512B rows, XOR-swizzled)
  __shared__ float sS[BM][68];      // 8.7KB S exchange
  __shared__ short sP[BM][80];      // 5KB P exchange
  __shared__ float sScale[BM];

  const int tid = threadIdx.x;
  const int lane = tid & 63;
  const int w = tid >> 6;
  const int wr = w >> 1, sp = w & 1;
  const int l15 = lane & 15;
  const int q0 = lane >> 4;
  const int crow = q0 * 4;

  // 512 blocks: XCDs 0-3 -> chunk 0, XCDs 4-7 -> chunk 1
  const int bid = blockIdx.x;
  const int chunk = (bid & 7) >> 2;
  const int rowblk = (bid >> 3) * 4 + (bid & 3);
  const int row0 = rowblk * BM;
  const int jbase = chunk * CHUNK;

  float ay4[4];
#pragma unroll
  for (int r = 0; r < 4; ++r) ay4[r] = ay[row0 + wr * 16 + crow + r];

  // ---- stage g block (once) + h tile 0, XOR-swizzled ----
#pragma unroll
  for (int R = 0; R < 4; ++R) {
    int dstb = R * 4096 + tid * 16;
    int lr = dstb >> 9;
    int srcb = (dstb & 511) ^ ((lr & 7) << 4);
    gl2lds16(gF + (row0 + lr) * DD + (srcb >> 1), (char*)sG + dstb);
  }
  auto stageH = [&](int jrow) {
#pragma unroll
    for (int R = 0; R < 8; ++R) {
      int dstb = R * 4096 + tid * 16;
      int lr = dstb >> 9;
      int srcb = (dstb & 511) ^ ((lr & 7) << 4);
      gl2lds16(hF + (jrow + lr) * DD + (srcb >> 1), (char*)sH + dstb);
    }
  };
  stageH(jbase);

  // packed adj: word (j0>>5)+sp of each row covers both cf halves (bit cf*16+l15)
  const size_t adjwb = (size_t)(row0 + wr * 16 + crow) * NW + sp;
  unsigned aw[4];
  float ax2[2];
  {
    int w0 = jbase >> 5;
#pragma unroll
    for (int r = 0; r < 4; ++r) aw[r] = adjp[adjwb + (size_t)r * NW + w0];
#pragma unroll
    for (int cf = 0; cf < 2; ++cf) ax2[cf] = ax[jbase + sp * 32 + cf * 16 + l15];
  }

  const int srow = tid >> 3;
  const int sc8 = (tid & 7) * 8;
  float m_run = -__builtin_inff();
  float l_run = 0.f;
  f32x4 accpv[2][4] = {};  // [rg][df]: rows rg*16+crow+r, dims w*64+df*16+l15

  BAR_VM();  // sG + sH(0) staged

  for (int t = 0; t < NT; ++t) {
    const int j0 = jbase + t * KVB;
    // ---- QK^T: single fp16 MFMA, A=g(LDS) B=h(LDS) ----
    f32x4 aA = {}, aB = {};
    {
      const int lrA = wr * 16 + l15;
      const int rbA = lrA * 512, swzA = (lrA & 7) << 4;
      const int lrB0 = sp * 32 + l15;
      const int rbB0 = lrB0 * 512, swzB0 = (lrB0 & 7) << 4;
      const int lrB1 = sp * 32 + 16 + l15;
      const int rbB1 = lrB1 * 512, swzB1 = (lrB1 & 7) << 4;
      __builtin_amdgcn_s_setprio(1);
#pragma unroll
      for (int kk = 0; kk < 8; ++kk) {
        const int slot = kk * 64 + q0 * 16;
        f16x8 ga = *(const f16x8*)((const char*)sG + rbA + (slot ^ swzA));
        f16x8 b0 = *(const f16x8*)((const char*)sH + rbB0 + (slot ^ swzB0));
        f16x8 b1 = *(const f16x8*)((const char*)sH + rbB1 + (slot ^ swzB1));
        aA = MFMA16(ga, b0, aA);
        aB = MFMA16(ga, b1, aB);
      }
      __builtin_amdgcn_s_setprio(0);
    }
    // ---- mask (packed bits) + bias + leaky -> sS ----
#pragma unroll
    for (int cf = 0; cf < 2; ++cf) {
      const f32x4& ac = cf ? aB : aA;
      const int bit = cf * 16 + l15;
#pragma unroll
      for (int r = 0; r < 4; ++r) {
        float v = ac[r] + ax2[cf] + ay4[r];
        v = (v > 0.f) ? v : 0.2f * v;
        sS[wr * 16 + crow + r][sp * 32 + cf * 16 + l15] =
            ((aw[r] >> bit) & 1u) ? v : -9.0e15f;
      }
    }
    BAR_LGKM();  // sS visible; sG/sH reads done
    // ---- vb + adj(t+1) issued BEFORE stage (vmcnt: PV waits only vb) ----
    f16x8 vb[2][4];
#pragma unroll
    for (int ks = 0; ks < 2; ++ks)
#pragma unroll
      for (int df = 0; df < 4; ++df)
        vb[ks][df] = *(const f16x8*)(fT + (size_t)(w * 64 + df * 16 + l15) * NN +
                                     j0 + ks * 32 + q0 * 8);
    unsigned awn[4];
    float ax2n[2];
    {
      int jn = (t + 1 < NT) ? (j0 + KVB) : jbase;
      int w0 = jn >> 5;
#pragma unroll
      for (int r = 0; r < 4; ++r) awn[r] = adjp[adjwb + (size_t)r * NW + w0];
#pragma unroll
      for (int cf = 0; cf < 2; ++cf) ax2n[cf] = ax[jn + sp * 32 + cf * 16 + l15];
    }
    if (t + 1 < NT) stageH(j0 + KVB);
    // ---- softmax: 8 threads/row, 8 cols each ----
    {
      float4 s0 = *(const float4*)(&sS[srow][sc8]);
      float4 s1 = *(const float4*)(&sS[srow][sc8 + 4]);
      float tmax = fmaxf(fmaxf(fmaxf(s0.x, s0.y), fmaxf(s0.z, s0.w)),
                         fmaxf(fmaxf(s1.x, s1.y), fmaxf(s1.z, s1.w)));
      tmax = fmaxf(tmax, __shfl_xor(tmax, 1));
      tmax = fmaxf(tmax, __shfl_xor(tmax, 2));
      tmax = fmaxf(tmax, __shfl_xor(tmax, 4));
      float m_new = fmaxf(m_run, tmax);
      float scale = __expf(m_run - m_new);
      float p[8];
      p[0] = __expf(s0.x - m_new); p[1] = __expf(s0.y - m_new);
      p[2] = __expf(s0.z - m_new); p[3] = __expf(s0.w - m_new);
      p[4] = __expf(s1.x - m_new); p[5] = __expf(s1.y - m_new);
      p[6] = __expf(s1.z - m_new); p[7] = __expf(s1.w - m_new);
      float psum = ((p[0] + p[1]) + (p[2] + p[3])) + ((p[4] + p[5]) + (p[6] + p[7]));
      psum += __shfl_xor(psum, 1);
      psum += __shfl_xor(psum, 2);
      psum += __shfl_xor(psum, 4);
      l_run = l_run * scale + psum;
      m_run = m_new;
      union { short s[8]; f16x8 v; } pu;
#pragma unroll
      for (int c = 0; c < 8; ++c) pu.s[c] = f2h(p[c]);
      *(f16x8*)(&sP[srow][sc8]) = pu.v;
      if ((tid & 7) == 0) sScale[srow] = scale;
    }
    BAR_LGKM();  // sP/sScale visible
    // ---- PV: rescale + 16 MFMA ----
    {
      float4 sc0 = *(const float4*)(&sScale[crow]);
      float4 sc1 = *(const float4*)(&sScale[16 + crow]);
      const float* scp[2] = { &sc0.x, &sc1.x };
#pragma unroll
      for (int rg = 0; rg < 2; ++rg)
#pragma unroll
        for (int df = 0; df < 4; ++df)
#pragma unroll
          for (int r = 0; r < 4; ++r) accpv[rg][df][r] *= scp[rg][r];
      __builtin_amdgcn_s_setprio(1);
#pragma unroll
      for (int ks = 0; ks < 2; ++ks) {
        f16x8 pa0 = *(const f16x8*)(&sP[l15][ks * 32 + q0 * 8]);
        f16x8 pa1 = *(const f16x8*)(&sP[16 + l15][ks * 32 + q0 * 8]);
#pragma unroll
        for (int df = 0; df < 4; ++df) {
          accpv[0][df] = MFMA16(pa0, vb[ks][df], accpv[0][df]);
          accpv[1][df] = MFMA16(pa1, vb[ks][df], accpv[1][df]);
        }
      }
      __builtin_amdgcn_s_setprio(0);
    }
    // rotate adj/ax prefetch
#pragma unroll
    for (int r = 0; r < 4; ++r) aw[r] = awn[r];
    ax2[0] = ax2n[0]; ax2[1] = ax2n[1];
    BAR_VM();  // stage(t+1) done; sP consumed; sS free
  }
  // ---- emit partials ----
  if ((tid & 7) == 0) {
    mPart[chunk * NN + row0 + srow] = m_run;
    lPart[chunk * NN + row0 + srow] = l_run;
  }
  short* np = numPart + (size_t)chunk * NN * DD;
#pragma unroll
  for (int rg = 0; rg < 2; ++rg)
#pragma unroll
    for (int df = 0; df < 4; ++df) {
      int col = w * 64 + df * 16 + l15;
#pragma unroll
      for (int r = 0; r < 4; ++r)
        np[(size_t)(row0 + rg * 16 + crow + r) * DD + col] = f2h(accpv[rg][df][r]);
    }
}

// hp = (sum_i num_i * exp(m_i - m*)) / (sum_i l_i * exp(m_i - m*))
__global__ __launch_bounds__(256) void combine_kernel(
    const short* __restrict__ numPart, const float* __restrict__ mPart,
    const float* __restrict__ lPart, short* __restrict__ hp) {
  const int row = blockIdx.x;
  const int col = threadIdx.x;
  float m[NPART], l[NPART];
  float ms = -__builtin_inff();
#pragma unroll
  for (int i = 0; i < NPART; ++i) {
    m[i] = mPart[i * NN + row];
    l[i] = lPart[i * NN + row];
    ms = fmaxf(ms, m[i]);
  }
  float denom = 0.f, num = 0.f;
  const size_t idx = (size_t)row * DD + col;
#pragma unroll
  for (int i = 0; i < NPART; ++i) {
    float wgt = __expf(m[i] - ms);
    denom += l[i] * wgt;
    num += h2f(numPart[(size_t)i * NN * DD + idx]) * wgt;
  }
  hp[idx] = f2h(num / denom);
}

extern "C" void kernel_launch(void* const* d_in, const int* in_sizes, int n_in,
                              void* d_out, int out_size, void* d_ws, size_t ws_size,
                              hipStream_t stream) {
  const float* feat = (const float*)d_in[0];
  const int*   adj  = (const int*)d_in[1];
  const float* W    = (const float*)d_in[2];
  const float* a1   = (const float*)d_in[3];
  const float* a2   = (const float*)d_in[4];
  const float* a12  = (const float*)d_in[5];
  const float* W1   = (const float*)d_in[6];
  const float* W2   = (const float*)d_in[7];
  float* out = (float*)d_out;
  (void)in_sizes; (void)n_in; (void)out_size; (void)ws_size;

  char* ws = (char*)d_ws;
  size_t off = 0;
  auto alloc = [&](size_t b) { void* p = ws + off; off += (b + 255) & ~(size_t)255; return p; };
  short* featHi = (short*)alloc((size_t)NN * DD * 2);
  short* featLo = (short*)alloc((size_t)NN * DD * 2);
  short* fT     = (short*)alloc((size_t)NN * DD * 2);
  short* hF     = (short*)alloc((size_t)NN * DD * 2);
  short* gF     = (short*)alloc((size_t)NN * DD * 2);
  short* hp     = (short*)alloc((size_t)NN * DD * 2);
  short* WTh    = (short*)alloc((size_t)DD * DD * 2);
  short* WTl    = (short*)alloc((size_t)DD * DD * 2);
  short* A12Th  = (short*)alloc((size_t)DD * DD * 2);
  short* A12Tl  = (short*)alloc((size_t)DD * DD * 2);
  short* W1T    = (short*)alloc((size_t)DD * DD * 2);
  short* W2T    = (short*)alloc((size_t)DD * DD * 2);
  float* axv    = (float*)alloc((size_t)NN * 4);
  float* ayv    = (float*)alloc((size_t)NN * 4);
  short* numPart = (short*)alloc((size_t)NPART * NN * DD * 2);
  float* mPart   = (float*)alloc((size_t)NPART * NN * 4);
  float* lPart   = (float*)alloc((size_t)NPART * NN * 4);
  unsigned* adjp = (unsigned*)alloc((size_t)NN * NW * 4);  // 8MB bitmask

  adjpack_kernel<<<NN * NW / 256, 256, 0, stream>>>(adj, adjp);
  cvt_split_kernel<<<2048, 256, 0, stream>>>(feat, featHi, featLo, NN * DD);
  featT_kernel<<<dim3(NN / 32, DD / 32), 256, 0, stream>>>(feat, fT);
  transpose_split_kernel<<<DD, DD, 0, stream>>>(W, WTh, WTl);
  transpose_split_kernel<<<DD, DD, 0, stream>>>(a12, A12Th, A12Tl);
  transpose_split_kernel<<<DD, DD, 0, stream>>>(W1, W1T, nullptr);
  transpose_split_kernel<<<DD, DD, 0, stream>>>(W2, W2T, nullptr);
  // h = feat @ W (split-fp16 3-term), stored fp16
  gemm_kernel<<<dim3(NN / 64, DD / 64), 256, 0, stream>>>(
      featHi, featLo, WTh, WTl, nullptr, nullptr, hF, nullptr, 0);
  // g = h @ a12 (2-term), stored fp16
  gemm_kernel<<<dim3(NN / 64, DD / 64), 256, 0, stream>>>(
      hF, nullptr, A12Th, A12Tl, nullptr, nullptr, gF, nullptr, 0);
  axay_kernel<<<NN / 4, 256, 0, stream>>>(hF, a1, a2, axv, ayv);
  attn_kernel<<<dim3((NN / BM) * NSPLIT), 256, 0, stream>>>(
      gF, hF, fT, axv, ayv, adjp, numPart, mPart, lPart);
  combine_kernel<<<NN, DD, 0, stream>>>(numPart, mPart, lPart, hp);
  // out = elu(feat@W1 + h'@W2)
  gemm_kernel<<<dim3(NN / 64, DD / 64), 256, 0, stream>>>(
      featHi, nullptr, W1T, nullptr, hp, W2T, nullptr, out, 1);
}

// Round 14
// 308.677 us; speedup vs baseline: 1.4448x; 1.0876x over previous
//
#include <hip/hip_runtime.h>

// GAT layer, N=8192, D=256. R14 = R13 attn structure, but raw adj read
// in-kernel with NON-TEMPORAL loads (no separate adjpack kernel).
//  - nt policy: adj streams through L2 evict-first -> h/fT stay resident
//    (R13 proved residence is worth ~30us; adjpack cost 45us -> fuse it away).
//  - sP row stride 80->72 shorts: PV ds_read_b128 4-way -> 2-way (free).
//  - otherwise byte-identical to R13: KVB=64, fp16 single-MFMA QK, NSPLIT=2,
//    vb-before-stage vmcnt discipline, XOR-swizzled LDS, XCD-half swizzle.

typedef __attribute__((ext_vector_type(8))) _Float16 f16x8;
typedef __attribute__((ext_vector_type(4))) float f32x4;

#define NN 8192
#define DD 256
#define NSPLIT 2
#define NPART 2
#define CHUNK (NN / NSPLIT)
#define KVB 64
#define BM 32
#define NT (CHUNK / KVB)

#define MFMA16(a, b, c) __builtin_amdgcn_mfma_f32_16x16x32_f16(a, b, c, 0, 0, 0)
#define BAR_LGKM() asm volatile("s_waitcnt lgkmcnt(0)\n\ts_barrier" ::: "memory")
#define BAR_VM() asm volatile("s_waitcnt vmcnt(0)\n\ts_barrier" ::: "memory")

__device__ __forceinline__ short f2h(float f) {
  union { _Float16 h; short s; } u; u.h = (_Float16)f; return u.s;
}
__device__ __forceinline__ float h2f(short b) {
  union { short s; _Float16 h; } u; u.s = b; return (float)u.h;
}

typedef __attribute__((address_space(3))) unsigned lds_u32;
typedef const __attribute__((address_space(1))) unsigned glb_u32;
__device__ __forceinline__ void gl2lds16(const void* g, void* l) {
  __builtin_amdgcn_global_load_lds((glb_u32*)g, (lds_u32*)l, 16, 0, 0);
}

// f32 -> (hi, lo) fp16 split, elementwise
__global__ __launch_bounds__(256) void cvt_split_kernel(const float* __restrict__ in,
                                                        short* __restrict__ hi,
                                                        short* __restrict__ lo, int n) {
  for (int i = blockIdx.x * blockDim.x + threadIdx.x; i < n; i += gridDim.x * blockDim.x) {
    float f = in[i];
    short h = f2h(f);
    hi[i] = h;
    lo[i] = f2h(f - h2f(h));
  }
}

// featT[c][i] = f16(feat[i][c]) via LDS 32x32 tile (coalesced both sides)
__global__ __launch_bounds__(256) void featT_kernel(const float* __restrict__ feat,
                                                    short* __restrict__ fT) {
  __shared__ float tile[32][33];
  const int i0 = blockIdx.x * 32, c0 = blockIdx.y * 32;
  const int r = threadIdx.x >> 5, c = threadIdx.x & 31;
#pragma unroll
  for (int p = 0; p < 4; ++p)
    tile[p * 8 + r][c] = feat[(size_t)(i0 + p * 8 + r) * DD + c0 + c];
  __syncthreads();
#pragma unroll
  for (int p = 0; p < 4; ++p)
    fT[(size_t)(c0 + p * 8 + r) * NN + i0 + c] = f2h(tile[c][p * 8 + r]);
}

// 256x256 f32 -> transposed fp16 (optionally split hi/lo)
__global__ __launch_bounds__(256) void transpose_split_kernel(const float* __restrict__ in,
                                                              short* __restrict__ tHi,
                                                              short* __restrict__ tLo) {
  int r = blockIdx.x, c = threadIdx.x;
  float f = in[r * DD + c];
  short h = f2h(f);
  tHi[c * DD + r] = h;
  if (tLo) tLo[c * DD + r] = f2h(f - h2f(h));
}

// C[64x64 tile] = A @ BT^T over K=256, fp16 MFMA (+split/second/ELU options)
__global__ __launch_bounds__(256) void gemm_kernel(
    const short* __restrict__ Ahi, const short* __restrict__ Alo,
    const short* __restrict__ BThi, const short* __restrict__ BTlo,
    const short* __restrict__ A2, const short* __restrict__ BT2,
    short* __restrict__ outH, float* __restrict__ outF, int doElu) {
  const int lane = threadIdx.x & 63;
  const int w = threadIdx.x >> 6;
  const int l15 = lane & 15;
  const int koff = (lane >> 4) * 8;
  const int row0 = blockIdx.x * 64 + w * 16;
  const int col0 = blockIdx.y * 64;
  f32x4 acc[4] = {};
  const int aoff = (row0 + l15) * DD + koff;
#pragma unroll
  for (int kk = 0; kk < 8; ++kk) {
    f16x8 ah = *(const f16x8*)(Ahi + aoff + kk * 32);
#pragma unroll
    for (int cf = 0; cf < 4; ++cf) {
      int boff = (col0 + cf * 16 + l15) * DD + kk * 32 + koff;
      f16x8 bh = *(const f16x8*)(BThi + boff);
      acc[cf] = MFMA16(ah, bh, acc[cf]);
      if (Alo) {
        f16x8 al = *(const f16x8*)(Alo + aoff + kk * 32);
        acc[cf] = MFMA16(al, bh, acc[cf]);
      }
      if (BTlo) {
        f16x8 bl = *(const f16x8*)(BTlo + boff);
        acc[cf] = MFMA16(ah, bl, acc[cf]);
      }
    }
  }
  if (A2) {
#pragma unroll
    for (int kk = 0; kk < 8; ++kk) {
      f16x8 ah = *(const f16x8*)(A2 + aoff + kk * 32);
#pragma unroll
      for (int cf = 0; cf < 4; ++cf) {
        f16x8 bh = *(const f16x8*)(BT2 + (col0 + cf * 16 + l15) * DD + kk * 32 + koff);
        acc[cf] = MFMA16(ah, bh, acc[cf]);
      }
    }
  }
  const int crow = row0 + (lane >> 4) * 4;
#pragma unroll
  for (int cf = 0; cf < 4; ++cf) {
    int col = col0 + cf * 16 + l15;
#pragma unroll
    for (int r = 0; r < 4; ++r) {
      float v = acc[cf][r];
      if (doElu) v = (v > 0.f) ? v : expm1f(v);
      if (outF) outF[(crow + r) * DD + col] = v;
      if (outH) outH[(crow + r) * DD + col] = f2h(v);
    }
  }
}

// ax[i] = h[i,:]·a1, ay[i] = h[i,:]·a2  (h fp16)
__global__ __launch_bounds__(256) void axay_kernel(const short* __restrict__ hF,
                                                   const float* __restrict__ a1,
                                                   const float* __restrict__ a2,
                                                   float* __restrict__ ax,
                                                   float* __restrict__ ay) {
  const int lane = threadIdx.x & 63;
  const int w = threadIdx.x >> 6;
  const int row = blockIdx.x * 4 + w;
  float s1 = 0.f, s2 = 0.f;
#pragma unroll
  for (int j = 0; j < 4; ++j) {
    int k = lane * 4 + j;
    float hv = h2f(hF[row * DD + k]);
    s1 += hv * a1[k];
    s2 += hv * a2[k];
  }
#pragma unroll
  for (int m = 1; m < 64; m <<= 1) {
    s1 += __shfl_xor(s1, m);
    s2 += __shfl_xor(s2, m);
  }
  if (lane == 0) { ax[row] = s1; ay[row] = s2; }
}

// Flash attention (R13 structure), raw adj via NON-TEMPORAL loads.
__global__ __launch_bounds__(256, 2) void attn_kernel(
    const short* __restrict__ gF, const short* __restrict__ hF,
    const short* __restrict__ fT, const float* __restrict__ ax,
    const float* __restrict__ ay, const int* __restrict__ adj,
    short* __restrict__ numPart, float* __restrict__ mPart,
    float* __restrict__ lPart) {
  __shared__ short sG[BM * DD];     // 16KB g tile (512B rows, XOR-swizzled)
  __shared__ short sH[KVB * DD];    // 32KB h tile (512B rows, XOR-swizzled)
  __shared__ float sS[BM][68];      // 8.7KB S exchange
  __shared__ short sP[BM][72];      // 4.5KB P exchange (144B rows: 2-way free)
  __shared__ float sScale[BM];

  const int tid = threadIdx.x;
  const int lane = tid & 63;
  const int w = tid >> 6;
  const int wr = w >> 1, sp = w & 1;
  const int l15 = lane & 15;
  const int q0 = lane >> 4;
  const int crow = q0 * 4;

  // 512 blocks: XCDs 0-3 -> chunk 0, XCDs 4-7 -> chunk 1
  const int bid = blockIdx.x;
  const int chunk = (bid & 7) >> 2;
  const int rowblk = (bid >> 3) * 4 + (bid & 3);
  const int row0 = rowblk * BM;
  const int jbase = chunk * CHUNK;

  float ay4[4];
#pragma unroll
  for (int r = 0; r < 4; ++r) ay4[r] = ay[row0 + wr * 16 + crow + r];

  // ---- stage g block (once) + h tile 0, XOR-swizzled ----
#pragma unroll
  for (int R = 0; R < 4; ++R) {
    int dstb = R * 4096 + tid * 16;
    int lr = dstb >> 9;
    int srcb = (dstb & 511) ^ ((lr & 7) << 4);
    gl2lds16(gF + (row0 + lr) * DD + (srcb >> 1), (char*)sG + dstb);
  }
  auto stageH = [&](int jrow) {
#pragma unroll
    for (int R = 0; R < 8; ++R) {
      int dstb = R * 4096 + tid * 16;
      int lr = dstb >> 9;
      int srcb = (dstb & 511) ^ ((lr & 7) << 4);
      gl2lds16(hF + (jrow + lr) * DD + (srcb >> 1), (char*)sH + dstb);
    }
  };
  stageH(jbase);

  // ---- raw adj, nt loads (evict-first: no L2 pollution), 1 tile ahead ----
  const size_t adjrow = (size_t)(row0 + wr * 16 + crow) * NN;
  int a8[2][4];
  float ax2[2];
#pragma unroll
  for (int cf = 0; cf < 2; ++cf) {
    int kb = jbase + sp * 32 + cf * 16 + l15;
    ax2[cf] = ax[kb];
#pragma unroll
    for (int r = 0; r < 4; ++r)
      a8[cf][r] = __builtin_nontemporal_load(adj + adjrow + (size_t)r * NN + kb);
  }

  const int srow = tid >> 3;
  const int sc8 = (tid & 7) * 8;
  float m_run = -__builtin_inff();
  float l_run = 0.f;
  f32x4 accpv[2][4] = {};  // [rg][df]: rows rg*16+crow+r, dims w*64+df*16+l15

  BAR_VM();  // sG + sH(0) staged

  for (int t = 0; t < NT; ++t) {
    const int j0 = jbase + t * KVB;
    // ---- QK^T: single fp16 MFMA, A=g(LDS) B=h(LDS) ----
    f32x4 aA = {}, aB = {};
    {
      const int lrA = wr * 16 + l15;
      const int rbA = lrA * 512, swzA = (lrA & 7) << 4;
      const int lrB0 = sp * 32 + l15;
      const int rbB0 = lrB0 * 512, swzB0 = (lrB0 & 7) << 4;
      const int lrB1 = sp * 32 + 16 + l15;
      const int rbB1 = lrB1 * 512, swzB1 = (lrB1 & 7) << 4;
      __builtin_amdgcn_s_setprio(1);
#pragma unroll
      for (int kk = 0; kk < 8; ++kk) {
        const int slot = kk * 64 + q0 * 16;
        f16x8 ga = *(const f16x8*)((const char*)sG + rbA + (slot ^ swzA));
        f16x8 b0 = *(const f16x8*)((const char*)sH + rbB0 + (slot ^ swzB0));
        f16x8 b1 = *(const f16x8*)((const char*)sH + rbB1 + (slot ^ swzB1));
        aA = MFMA16(ga, b0, aA);
        aB = MFMA16(ga, b1, aB);
      }
      __builtin_amdgcn_s_setprio(0);
    }
    // ---- mask + bias + leaky -> sS ----
#pragma unroll
    for (int cf = 0; cf < 2; ++cf) {
      const f32x4& ac = cf ? aB : aA;
#pragma unroll
      for (int r = 0; r < 4; ++r) {
        float v = ac[r] + ax2[cf] + ay4[r];
        v = (v > 0.f) ? v : 0.2f * v;
        sS[wr * 16 + crow + r][sp * 32 + cf * 16 + l15] =
            (a8[cf][r] > 0) ? v : -9.0e15f;
      }
    }
    BAR_LGKM();  // sS visible; sG/sH reads done
    // ---- vb + adj(t+1) issued BEFORE stage (PV's vmcnt waits only vb) ----
    f16x8 vb[2][4];
#pragma unroll
    for (int ks = 0; ks < 2; ++ks)
#pragma unroll
      for (int df = 0; df < 4; ++df)
        vb[ks][df] = *(const f16x8*)(fT + (size_t)(w * 64 + df * 16 + l15) * NN +
                                     j0 + ks * 32 + q0 * 8);
    int a8n[2][4];
    float ax2n[2];
    {
      int jn = (t + 1 < NT) ? (j0 + KVB) : jbase;
#pragma unroll
      for (int cf = 0; cf < 2; ++cf) {
        int kb = jn + sp * 32 + cf * 16 + l15;
        ax2n[cf] = ax[kb];
#pragma unroll
        for (int r = 0; r < 4; ++r)
          a8n[cf][r] = __builtin_nontemporal_load(adj + adjrow + (size_t)r * NN + kb);
      }
    }
    if (t + 1 < NT) stageH(j0 + KVB);
    // ---- softmax: 8 threads/row, 8 cols each ----
    {
      float4 s0 = *(const float4*)(&sS[srow][sc8]);
      float4 s1 = *(const float4*)(&sS[srow][sc8 + 4]);
      float tmax = fmaxf(fmaxf(fmaxf(s0.x, s0.y), fmaxf(s0.z, s0.w)),
                         fmaxf(fmaxf(s1.x, s1.y), fmaxf(s1.z, s1.w)));
      tmax = fmaxf(tmax, __shfl_xor(tmax, 1));
      tmax = fmaxf(tmax, __shfl_xor(tmax, 2));
      tmax = fmaxf(tmax, __shfl_xor(tmax, 4));
      float m_new = fmaxf(m_run, tmax);
      float scale = __expf(m_run - m_new);
      float p[8];
      p[0] = __expf(s0.x - m_new); p[1] = __expf(s0.y - m_new);
      p[2] = __expf(s0.z - m_new); p[3] = __expf(s0.w - m_new);
      p[4] = __expf(s1.x - m_new); p[5] = __expf(s1.y - m_new);
      p[6] = __expf(s1.z - m_new); p[7] = __expf(s1.w - m_new);
      float psum = ((p[0] + p[1]) + (p[2] + p[3])) + ((p[4] + p[5]) + (p[6] + p[7]));
      psum += __shfl_xor(psum, 1);
      psum += __shfl_xor(psum, 2);
      psum += __shfl_xor(psum, 4);
      l_run = l_run * scale + psum;
      m_run = m_new;
      union { short s[8]; f16x8 v; } pu;
#pragma unroll
      for (int c = 0; c < 8; ++c) pu.s[c] = f2h(p[c]);
      *(f16x8*)(&sP[srow][sc8]) = pu.v;
      if ((tid & 7) == 0) sScale[srow] = scale;
    }
    BAR_LGKM();  // sP/sScale visible
    // ---- PV: rescale + 16 MFMA ----
    {
      float4 sc0 = *(const float4*)(&sScale[crow]);
      float4 sc1 = *(const float4*)(&sScale[16 + crow]);
      const float* scp[2] = { &sc0.x, &sc1.x };
#pragma unroll
      for (int rg = 0; rg < 2; ++rg)
#pragma unroll
        for (int df = 0; df < 4; ++df)
#pragma unroll
          for (int r = 0; r < 4; ++r) accpv[rg][df][r] *= scp[rg][r];
      __builtin_amdgcn_s_setprio(1);
#pragma unroll
      for (int ks = 0; ks < 2; ++ks) {
        f16x8 pa0 = *(const f16x8*)(&sP[l15][ks * 32 + q0 * 8]);
        f16x8 pa1 = *(const f16x8*)(&sP[16 + l15][ks * 32 + q0 * 8]);
#pragma unroll
        for (int df = 0; df < 4; ++df) {
          accpv[0][df] = MFMA16(pa0, vb[ks][df], accpv[0][df]);
          accpv[1][df] = MFMA16(pa1, vb[ks][df], accpv[1][df]);
        }
      }
      __builtin_amdgcn_s_setprio(0);
    }
    // rotate adj/ax prefetch
#pragma unroll
    for (int cf = 0; cf < 2; ++cf) {
#pragma unroll
      for (int r = 0; r < 4; ++r) a8[cf][r] = a8n[cf][r];
      ax2[cf] = ax2n[cf];
    }
    BAR_VM();  // stage(t+1) done; sP consumed; sS free
  }
  // ---- emit partials ----
  if ((tid & 7) == 0) {
    mPart[chunk * NN + row0 + srow] = m_run;
    lPart[chunk * NN + row0 + srow] = l_run;
  }
  short* np = numPart + (size_t)chunk * NN * DD;
#pragma unroll
  for (int rg = 0; rg < 2; ++rg)
#pragma unroll
    for (int df = 0; df < 4; ++df) {
      int col = w * 64 + df * 16 + l15;
#pragma unroll
      for (int r = 0; r < 4; ++r)
        np[(size_t)(row0 + rg * 16 + crow + r) * DD + col] = f2h(accpv[rg][df][r]);
    }
}

// hp = (sum_i num_i * exp(m_i - m*)) / (sum_i l_i * exp(m_i - m*))
__global__ __launch_bounds__(256) void combine_kernel(
    const short* __restrict__ numPart, const float* __restrict__ mPart,
    const float* __restrict__ lPart, short* __restrict__ hp) {
  const int row = blockIdx.x;
  const int col = threadIdx.x;
  float m[NPART], l[NPART];
  float ms = -__builtin_inff();
#pragma unroll
  for (int i = 0; i < NPART; ++i) {
    m[i] = mPart[i * NN + row];
    l[i] = lPart[i * NN + row];
    ms = fmaxf(ms, m[i]);
  }
  float denom = 0.f, num = 0.f;
  const size_t idx = (size_t)row * DD + col;
#pragma unroll
  for (int i = 0; i < NPART; ++i) {
    float wgt = __expf(m[i] - ms);
    denom += l[i] * wgt;
    num += h2f(numPart[(size_t)i * NN * DD + idx]) * wgt;
  }
  hp[idx] = f2h(num / denom);
}

extern "C" void kernel_launch(void* const* d_in, const int* in_sizes, int n_in,
                              void* d_out, int out_size, void* d_ws, size_t ws_size,
                              hipStream_t stream) {
  const float* feat = (const float*)d_in[0];
  const int*   adj  = (const int*)d_in[1];
  const float* W    = (const float*)d_in[2];
  const float* a1   = (const float*)d_in[3];
  const float* a2   = (const float*)d_in[4];
  const float* a12  = (const float*)d_in[5];
  const float* W1   = (const float*)d_in[6];
  const float* W2   = (const float*)d_in[7];
  float* out = (float*)d_out;
  (void)in_sizes; (void)n_in; (void)out_size; (void)ws_size;

  char* ws = (char*)d_ws;
  size_t off = 0;
  auto alloc = [&](size_t b) { void* p = ws + off; off += (b + 255) & ~(size_t)255; return p; };
  short* featHi = (short*)alloc((size_t)NN * DD * 2);
  short* featLo = (short*)alloc((size_t)NN * DD * 2);
  short* fT     = (short*)alloc((size_t)NN * DD * 2);
  short* hF     = (short*)alloc((size_t)NN * DD * 2);
  short* gF     = (short*)alloc((size_t)NN * DD * 2);
  short* hp     = (short*)alloc((size_t)NN * DD * 2);
  short* WTh    = (short*)alloc((size_t)DD * DD * 2);
  short* WTl    = (short*)alloc((size_t)DD * DD * 2);
  short* A12Th  = (short*)alloc((size_t)DD * DD * 2);
  short* A12Tl  = (short*)alloc((size_t)DD * DD * 2);
  short* W1T    = (short*)alloc((size_t)DD * DD * 2);
  short* W2T    = (short*)alloc((size_t)DD * DD * 2);
  float* axv    = (float*)alloc((size_t)NN * 4);
  float* ayv    = (float*)alloc((size_t)NN * 4);
  short* numPart = (short*)alloc((size_t)NPART * NN * DD * 2);
  float* mPart   = (float*)alloc((size_t)NPART * NN * 4);
  float* lPart   = (float*)alloc((size_t)NPART * NN * 4);

  cvt_split_kernel<<<2048, 256, 0, stream>>>(feat, featHi, featLo, NN * DD);
  featT_kernel<<<dim3(NN / 32, DD / 32), 256, 0, stream>>>(feat, fT);
  transpose_split_kernel<<<DD, DD, 0, stream>>>(W, WTh, WTl);
  transpose_split_kernel<<<DD, DD, 0, stream>>>(a12, A12Th, A12Tl);
  transpose_split_kernel<<<DD, DD, 0, stream>>>(W1, W1T, nullptr);
  transpose_split_kernel<<<DD, DD, 0, stream>>>(W2, W2T, nullptr);
  // h = feat @ W (split-fp16 3-term), stored fp16
  gemm_kernel<<<dim3(NN / 64, DD / 64), 256, 0, stream>>>(
      featHi, featLo, WTh, WTl, nullptr, nullptr, hF, nullptr, 0);
  // g = h @ a12 (2-term), stored fp16
  gemm_kernel<<<dim3(NN / 64, DD / 64), 256, 0, stream>>>(
      hF, nullptr, A12Th, A12Tl, nullptr, nullptr, gF, nullptr, 0);
  axay_kernel<<<NN / 4, 256, 0, stream>>>(hF, a1, a2, axv, ayv);
  attn_kernel<<<dim3((NN / BM) * NSPLIT), 256, 0, stream>>>(
      gF, hF, fT, axv, ayv, adj, numPart, mPart, lPart);
  combine_kernel<<<NN, DD, 0, stream>>>(numPart, mPart, lPart, hp);
  // out = elu(feat@W1 + h'@W2)
  gemm_kernel<<<dim3(NN / 64, DD / 64), 256, 0, stream>>>(
      featHi, nullptr, W1T, nullptr, hp, W2T, nullptr, out, 1);
}